// Round 5
// baseline (126.638 us; speedup 1.0000x reference)
//
#include <hip/hip_runtime.h>
#include <hip/hip_bf16.h>

#define Bdim 4
#define Tdim 2048
#define Wdim 1024
#define Kdim 7
#define Gdim 8
#define Cg   128
#define Hdim 64   // W / SE_R
#define TT   128  // t-rows per conv block

typedef __attribute__((ext_vector_type(8))) short short8v;
typedef __attribute__((ext_vector_type(4))) float float4v;

__device__ __forceinline__ short f2bf(float x) {          // RNE
    union { float f; unsigned u; } v; v.f = x;
    unsigned r = v.u + 0x7fff + ((v.u >> 16) & 1);
    return (short)(r >> 16);
}

// lerp two bf16x8 (as uint4) in fp32, repack to bf16x8 (round-half-up)
__device__ __forceinline__ short8v lerp_pack(uint4 a, uint4 b, float f) {
    union { uint4 u; short8v s; } r;
    const unsigned* pa = (const unsigned*)&a;
    const unsigned* pb = (const unsigned*)&b;
    unsigned* pr = (unsigned*)&r.u;
#pragma unroll
    for (int d = 0; d < 4; d++) {
        float alo = __uint_as_float(pa[d] << 16);
        float ahi = __uint_as_float(pa[d] & 0xffff0000u);
        float blo = __uint_as_float(pb[d] << 16);
        float bhi = __uint_as_float(pb[d] & 0xffff0000u);
        float rlo = alo + f * (blo - alo);
        float rhi = ahi + f * (bhi - ahi);
        unsigned ulo = __float_as_uint(rlo) + 0x8000u;
        unsigned uhi = __float_as_uint(rhi) + 0x8000u;
        pr[d] = __builtin_amdgcn_perm(uhi, ulo, 0x07060302u);
    }
    return r.s;
}

// ---------------- K_pre: weights->bf16 swizzled  +  offsets GEMV + h->bf16 ----------------
__global__ __launch_bounds__(256) void k_pre(const float* __restrict__ conv_w,
                                             short* __restrict__ Wtb,
                                             const float* __restrict__ h,
                                             const float* __restrict__ offset_w,
                                             const float* __restrict__ offset_b,
                                             float* __restrict__ pos,
                                             ushort* __restrict__ h16) {
    int tid = threadIdx.x;
    if (blockIdx.x < 448) {
        int i = blockIdx.x * 256 + tid;
        if (i >= Gdim * Kdim * Cg * 16) return;
        int cb = i & 15;
        int o = (i >> 4) & 127;
        int gk = i >> 11;                            // g*7 + k
        int k = gk % Kdim, g = gk / Kdim;
        const float* src = conv_w + ((size_t)(g * Cg + o) * Cg + cb * 8) * Kdim + k;
        short8v pk;
#pragma unroll
        for (int j = 0; j < 8; j++) pk[j] = f2bf(src[(size_t)j * Kdim]);
        short8v* Wtb8 = (short8v*)Wtb;
        Wtb8[(size_t)gk * 2048 + o * 16 + (cb ^ (o & 7))] = pk;
        return;
    }
    // offsets + h16: one wave per row, 4 rows per block
    int lane = tid & 63, wv = tid >> 6;
    int bt = (blockIdx.x - 448) * 4 + wv;            // b*T + t
    int t = bt & (Tdim - 1);
    const float* row = h + (size_t)bt * Wdim;
    float acc[Kdim];
#pragma unroll
    for (int k = 0; k < Kdim; k++) acc[k] = 0.f;
#pragma unroll
    for (int j = 0; j < 4; j++) {
        int c = lane * 4 + j * 256;
        float4 hv = *(const float4*)(row + c);
        const float* ow = offset_w + (size_t)c * Kdim;
#pragma unroll
        for (int k = 0; k < Kdim; k++)
            acc[k] += hv.x * ow[k] + hv.y * ow[Kdim + k] + hv.z * ow[2 * Kdim + k]
                    + hv.w * ow[3 * Kdim + k];
        ushort4 hp;
        hp.x = (ushort)f2bf(hv.x); hp.y = (ushort)f2bf(hv.y);
        hp.z = (ushort)f2bf(hv.z); hp.w = (ushort)f2bf(hv.w);
        *(ushort4*)(h16 + (size_t)bt * Wdim + c) = hp;
    }
#pragma unroll
    for (int k = 0; k < Kdim; k++) {
#pragma unroll
        for (int m = 32; m > 0; m >>= 1) acc[k] += __shfl_xor(acc[k], m);
    }
    if (lane < Kdim) {
        float o = acc[lane] + offset_b[lane];
        float base = (float)t + (float)(lane - 3);
        float p = fminf(fmaxf(base + o, 0.f), (float)(Tdim - 1));
        pos[bt * Kdim + lane] = p;
    }
}

// ---------------- K2: deformable grouped conv, A in-register, B dbuf in LDS ----------------
// grid: ((b*16 + tc)*8 + g)*2 + oh ; 256 thr = 4 waves; wave = 32t x 64o
__global__ __launch_bounds__(256, 4) void k_conv(const ushort* __restrict__ h16,
                                                 const short* __restrict__ Wtb,
                                                 const float* __restrict__ conv_b,
                                                 const float* __restrict__ pos,
                                                 ushort* __restrict__ y16) {
    __shared__ short8v sB8[2][64 * 16];   // 2 x 16 KB

    int blk = blockIdx.x;
    int oh = blk & 1;
    int g  = (blk >> 1) & 7;
    int tc = (blk >> 4) & 15;
    int b  = blk >> 8;
    int t0 = tc * TT;
    int tid = threadIdx.x;
    int lane = tid & 63, wv = tid >> 6;
    int r15 = lane & 15, q = lane >> 4;

    int rowA = t0 + wv * 32 + r15;
    int rowB = rowA + 16;
    float posA[Kdim], posB[Kdim];
    const float* pA = pos + (b * Tdim + rowA) * Kdim;
    const float* pB = pos + (b * Tdim + rowB) * Kdim;
#pragma unroll
    for (int k = 0; k < Kdim; k++) { posA[k] = pA[k]; posB[k] = pB[k]; }

    const ushort* hb = h16 + (size_t)(b * Tdim) * Wdim + g * Cg;
    const short8v* WtbV = (const short8v*)Wtb;
#define WK(kk_) (WtbV + (((size_t)(g * Kdim + (kk_)) * 128 + oh * 64) << 4))

    float4v acc[2][4];
#pragma unroll
    for (int tt = 0; tt < 2; tt++)
#pragma unroll
        for (int n = 0; n < 4; n++) acc[tt][n] = (float4v){0.f, 0.f, 0.f, 0.f};

    // prologue: stage B(0) into buf0
    {
        const short8v* wk = WK(0);
        short8v st[4];
#pragma unroll
        for (int i = 0; i < 4; i++) st[i] = wk[i * 256 + tid];
#pragma unroll
        for (int i = 0; i < 4; i++) sB8[0][i * 256 + tid] = st[i];
    }

#pragma unroll 1
    for (int k = 0; k < Kdim; k++) {
        __syncthreads();
        int cur = k & 1;
        // ---- A ttile0 loads ----
        float pv0 = posA[k];
        int p00 = (int)pv0; float f0 = pv0 - (float)p00;
        int p01 = min(p00 + 1, Tdim - 1);
        const uint4* r00 = (const uint4*)(hb + (size_t)p00 * Wdim);
        const uint4* r01 = (const uint4*)(hb + (size_t)p01 * Wdim);
        uint4 a0[4], a1[4];
#pragma unroll
        for (int kk = 0; kk < 4; kk++) {
            int u = kk * 4 + q;
            a0[kk] = r00[u];
            a1[kk] = r01[u];
        }
        // ---- B(k+1) stage loads (stay in flight under interp) ----
        short8v st[4];
        if (k < Kdim - 1) {
            const short8v* wk = WK(k + 1);
#pragma unroll
            for (int i = 0; i < 4; i++) st[i] = wk[i * 256 + tid];
        }
        // ---- interp ttile0 ----
        short8v frg0[4];
#pragma unroll
        for (int kk = 0; kk < 4; kk++) frg0[kk] = lerp_pack(a0[kk], a1[kk], f0);
        // ---- A ttile1 loads + interp ----
        float pv1 = posB[k];
        int p10 = (int)pv1; float f1 = pv1 - (float)p10;
        int p11 = min(p10 + 1, Tdim - 1);
        const uint4* r10 = (const uint4*)(hb + (size_t)p10 * Wdim);
        const uint4* r11 = (const uint4*)(hb + (size_t)p11 * Wdim);
#pragma unroll
        for (int kk = 0; kk < 4; kk++) {
            int u = kk * 4 + q;
            a0[kk] = r10[u];
            a1[kk] = r11[u];
        }
        short8v frg1[4];
#pragma unroll
        for (int kk = 0; kk < 4; kk++) frg1[kk] = lerp_pack(a0[kk], a1[kk], f1);
        // ---- MFMA: 4 k-slices x 4 o-tiles x 2 t-tiles ----
#pragma unroll
        for (int kk = 0; kk < 4; kk++) {
            int cs = kk * 4 + q;
#pragma unroll
            for (int n = 0; n < 4; n++) {
                int orow = n * 16 + r15;
                short8v bf = sB8[cur][orow * 16 + (cs ^ (orow & 7))];
                acc[0][n] = __builtin_amdgcn_mfma_f32_16x16x32_bf16(frg0[kk], bf, acc[0][n], 0, 0, 0);
                acc[1][n] = __builtin_amdgcn_mfma_f32_16x16x32_bf16(frg1[kk], bf, acc[1][n], 0, 0, 0);
            }
        }
        // ---- write staged B(k+1) ----
        if (k < Kdim - 1) {
#pragma unroll
            for (int i = 0; i < 4; i++) sB8[cur ^ 1][i * 256 + tid] = st[i];
        }
    }
    // ---- epilogue ----
#pragma unroll
    for (int n = 0; n < 4; n++) {
        int col = g * Cg + oh * 64 + n * 16 + r15;
        float bias = conv_b[col];
#pragma unroll
        for (int tt = 0; tt < 2; tt++) {
            int trow = t0 + wv * 32 + tt * 16 + q * 4;
#pragma unroll
            for (int j = 0; j < 4; j++)
                y16[(size_t)(b * Tdim + trow + j) * Wdim + col] =
                    (ushort)f2bf(acc[tt][n][j] + bias);
        }
    }
}

// ---------------- K3: LN + masked pool, wave-per-row, atomic accumulate ----------------
// grid = Bdim*64, block = 256 (4 waves x 8 rows)
__global__ __launch_bounds__(256) void k_lnpool(const ushort* __restrict__ y16,
                                                const int* __restrict__ mask,
                                                float* __restrict__ s_sum) {
    int blk = blockIdx.x;
    int b = blk >> 6, ch = blk & 63;
    int tid = threadIdx.x;
    int lane = tid & 63, wv = tid >> 6;
    __shared__ float red[4 * Wdim];      // 16 KB

    float accv[2][8];
#pragma unroll
    for (int j = 0; j < 2; j++)
#pragma unroll
        for (int e = 0; e < 8; e++) accv[j][e] = 0.f;

    for (int i = 0; i < 8; i++) {
        int t = ch * 32 + wv * 8 + i;
        if (mask[b * Tdim + t]) continue;
        const ushort* yr = y16 + (size_t)(b * Tdim + t) * Wdim;
        float v[2][8];
        float s = 0.f, qq = 0.f;
#pragma unroll
        for (int j = 0; j < 2; j++) {
            uint4 u = *(const uint4*)(yr + lane * 8 + j * 512);
            const unsigned* pu = (const unsigned*)&u;
#pragma unroll
            for (int d = 0; d < 4; d++) {
                float lo = __uint_as_float(pu[d] << 16);
                float hi = __uint_as_float(pu[d] & 0xffff0000u);
                v[j][d * 2] = lo; v[j][d * 2 + 1] = hi;
                s += lo + hi; qq += lo * lo + hi * hi;
            }
        }
#pragma unroll
        for (int m = 32; m > 0; m >>= 1) { s += __shfl_xor(s, m); qq += __shfl_xor(qq, m); }
        float mu = s * (1.f / Wdim);
        float inv = rsqrtf(qq * (1.f / Wdim) - mu * mu + 1e-5f);
#pragma unroll
        for (int j = 0; j < 2; j++)
#pragma unroll
            for (int e = 0; e < 8; e++) accv[j][e] += (v[j][e] - mu) * inv;
    }
    // combine 4 waves in LDS, then one atomic per channel per block
#pragma unroll
    for (int j = 0; j < 2; j++)
        *(float4*)(&red[wv * Wdim + lane * 8 + j * 512]) =
            (float4){accv[j][0], accv[j][1], accv[j][2], accv[j][3]};
#pragma unroll
    for (int j = 0; j < 2; j++)
        *(float4*)(&red[wv * Wdim + lane * 8 + j * 512 + 4]) =
            (float4){accv[j][4], accv[j][5], accv[j][6], accv[j][7]};
    __syncthreads();
#pragma unroll
    for (int e = 0; e < 4; e++) {
        int w = tid + e * 256;
        float a = red[w] + red[Wdim + w] + red[2 * Wdim + w] + red[3 * Wdim + w];
        atomicAdd(&s_sum[b * Wdim + w], a);
    }
}

// ---------------- K4: SE MLP + final projection -> out[b] ----------------
__global__ __launch_bounds__(256) void k_sefinal(const float* __restrict__ s_sum,
                                                 const int* __restrict__ mask,
                                                 const float* __restrict__ ln_g,
                                                 const float* __restrict__ ln_b,
                                                 const float* __restrict__ w1,
                                                 const float* __restrict__ b1,
                                                 const float* __restrict__ w2,
                                                 const float* __restrict__ b2,
                                                 const float* __restrict__ projw,
                                                 const float* __restrict__ projb,
                                                 float* __restrict__ out) {
    int b = blockIdx.x, tid = threadIdx.x;
    __shared__ float s[Wdim];
    __shared__ float hred[4][Hdim];
    __shared__ float hid[Hdim];
    __shared__ float rbuf[4];
    __shared__ float sLinv;
    int lane = tid & 63, wv = tid >> 6;

    int cnt = 0;
    for (int t = tid; t < Tdim; t += 256) cnt += (mask[b * Tdim + t] ? 0 : 1);
    float fc = (float)cnt;
#pragma unroll
    for (int off = 32; off > 0; off >>= 1) fc += __shfl_down(fc, off);
    if (lane == 0) rbuf[wv] = fc;
    __syncthreads();
    if (tid == 0) {
        float L = rbuf[0] + rbuf[1] + rbuf[2] + rbuf[3];
        sLinv = 1.f / fmaxf(L, 1.f);
    }
    __syncthreads();
    float Linv = sLinv;

    int w4 = tid * 4;
    float4 a = *(const float4*)(s_sum + b * Wdim + w4);
    float4 gg = *(const float4*)(ln_g + w4);
    float4 bb = *(const float4*)(ln_b + w4);
    s[w4 + 0] = gg.x * (a.x * Linv) + bb.x;
    s[w4 + 1] = gg.y * (a.y * Linv) + bb.y;
    s[w4 + 2] = gg.z * (a.z * Linv) + bb.z;
    s[w4 + 3] = gg.w * (a.w * Linv) + bb.w;
    __syncthreads();

    int j = tid & 63, p = tid >> 6;
    float ha = 0.f;
    for (int w = p * 256; w < (p + 1) * 256; ++w) ha += s[w] * w1[(size_t)w * Hdim + j];
    hred[p][j] = ha;
    __syncthreads();
    if (tid < Hdim)
        hid[tid] = fmaxf(hred[0][tid] + hred[1][tid] + hred[2][tid] + hred[3][tid] + b1[tid], 0.f);
    __syncthreads();

    float part = 0.f;
    for (int w = tid; w < Wdim; w += 256) {
        float ga = b2[w];
#pragma unroll 8
        for (int j2 = 0; j2 < Hdim; j2++) ga += hid[j2] * w2[(size_t)j2 * Wdim + w];
        float gate = 1.f / (1.f + expf(-ga));
        part += s[w] * gate * projw[w];
    }
#pragma unroll
    for (int off = 32; off > 0; off >>= 1) part += __shfl_down(part, off);
    __syncthreads();
    if (lane == 0) rbuf[wv] = part;
    __syncthreads();
    if (tid == 0) out[b] = rbuf[0] + rbuf[1] + rbuf[2] + rbuf[3] + projb[0];
}

extern "C" void kernel_launch(void* const* d_in, const int* in_sizes, int n_in,
                              void* d_out, int out_size, void* d_ws, size_t ws_size,
                              hipStream_t stream) {
    const float* h        = (const float*)d_in[0];
    const int*   mask     = (const int*)d_in[1];
    const float* offset_w = (const float*)d_in[2];
    const float* offset_b = (const float*)d_in[3];
    const float* conv_w   = (const float*)d_in[4];
    const float* conv_b   = (const float*)d_in[5];
    const float* ln_g     = (const float*)d_in[6];
    const float* ln_b     = (const float*)d_in[7];
    const float* se_w1    = (const float*)d_in[8];
    const float* se_b1    = (const float*)d_in[9];
    const float* se_w2    = (const float*)d_in[10];
    const float* se_b2    = (const float*)d_in[11];
    const float* proj_w   = (const float*)d_in[12];
    const float* proj_b   = (const float*)d_in[13];
    float* out = (float*)d_out;

    char* wsb = (char*)d_ws;
    float*  pos   = (float*)(wsb);                    //    229,376 B
    ushort* h16   = (ushort*)(wsb + 229376);          // 16,777,216 B
    short*  Wtb   = (short*)(wsb + 17006592);         //  1,835,008 B
    ushort* y16   = (ushort*)(wsb + 18841600);        // 16,777,216 B
    float*  s_sum = (float*)(wsb + 35618816);         //     16,384 B (total ~34 MB)

    hipMemsetAsync(s_sum, 0, Bdim * Wdim * sizeof(float), stream);
    k_pre<<<dim3(448 + Bdim * Tdim / 4), dim3(256), 0, stream>>>(conv_w, Wtb, h, offset_w,
                                                                 offset_b, pos, h16);
    k_conv<<<dim3(Bdim * (Tdim / TT) * Gdim * 2), dim3(256), 0, stream>>>(h16, Wtb, conv_b,
                                                                          pos, y16);
    k_lnpool<<<dim3(Bdim * 64), dim3(256), 0, stream>>>(y16, mask, s_sum);
    k_sefinal<<<dim3(Bdim), dim3(256), 0, stream>>>(s_sum, mask, ln_g, ln_b,
                                                    se_w1, se_b1, se_w2, se_b2,
                                                    proj_w, proj_b, out);
}

// Round 6
// 99.047 us; speedup vs baseline: 1.2786x; 1.2786x over previous
//
#include <hip/hip_runtime.h>
#include <hip/hip_bf16.h>

#define Bdim 4
#define Tdim 2048
#define Wdim 1024
#define Kdim 7
#define Gdim 8
#define Cg   128
#define Hdim 64   // W / SE_R
#define TT   64   // t-rows per conv block

typedef __attribute__((ext_vector_type(8))) short short8v;
typedef __attribute__((ext_vector_type(4))) float float4v;

__device__ __forceinline__ short f2bf(float x) {          // RNE
    union { float f; unsigned u; } v; v.f = x;
    unsigned r = v.u + 0x7fff + ((v.u >> 16) & 1);
    return (short)(r >> 16);
}

__device__ __forceinline__ unsigned pack2bf(float lo, float hi) {  // round-half-up
    return __builtin_amdgcn_perm(__float_as_uint(hi) + 0x8000u,
                                 __float_as_uint(lo) + 0x8000u, 0x07060302u);
}

// lerp two bf16x8 (as uint4) in fp32, repack to bf16x8
__device__ __forceinline__ short8v lerp_pack(uint4 a, uint4 b, float f) {
    union { uint4 u; short8v s; } r;
    const unsigned* pa = (const unsigned*)&a;
    const unsigned* pb = (const unsigned*)&b;
    unsigned* pr = (unsigned*)&r.u;
#pragma unroll
    for (int d = 0; d < 4; d++) {
        float alo = __uint_as_float(pa[d] << 16);
        float ahi = __uint_as_float(pa[d] & 0xffff0000u);
        float blo = __uint_as_float(pb[d] << 16);
        float bhi = __uint_as_float(pb[d] & 0xffff0000u);
        float rlo = alo + f * (blo - alo);
        float rhi = ahi + f * (bhi - ahi);
        pr[d] = pack2bf(rlo, rhi);
    }
    return r.s;
}

// ---------------- K_pre: weights->bf16 linear + s_sum zero + offsets GEMV + h->bf16 ----------------
__global__ __launch_bounds__(256) void k_pre(const float* __restrict__ conv_w,
                                             short* __restrict__ Wtb,
                                             const float* __restrict__ h,
                                             const float* __restrict__ offset_w,
                                             const float* __restrict__ offset_b,
                                             float* __restrict__ pos,
                                             ushort* __restrict__ h16,
                                             float* __restrict__ s_sum) {
    int tid = threadIdx.x;
    if (blockIdx.x < 448) {
        if (blockIdx.x == 0) {
#pragma unroll
            for (int i = 0; i < 16; i++) s_sum[tid + i * 256] = 0.f;
        }
        int i = blockIdx.x * 256 + tid;
        int cb = i & 15;
        int o = (i >> 4) & 127;
        int gk = i >> 11;                            // g*7 + k
        int k = gk % Kdim, g = gk / Kdim;
        const float* src = conv_w + ((size_t)(g * Cg + o) * Cg + cb * 8) * Kdim + k;
        short8v pk;
#pragma unroll
        for (int j = 0; j < 8; j++) pk[j] = f2bf(src[(size_t)j * Kdim]);
        short8v* Wtb8 = (short8v*)Wtb;
        Wtb8[(size_t)gk * 2048 + o * 16 + cb] = pk;   // LINEAR layout
        return;
    }
    // offsets + h16: one wave per row, 4 rows per block
    int lane = tid & 63, wv = tid >> 6;
    int bt = (blockIdx.x - 448) * 4 + wv;            // b*T + t
    int t = bt & (Tdim - 1);
    const float* row = h + (size_t)bt * Wdim;
    float acc[Kdim];
#pragma unroll
    for (int k = 0; k < Kdim; k++) acc[k] = 0.f;
#pragma unroll
    for (int j = 0; j < 4; j++) {
        int c = lane * 4 + j * 256;
        float4 hv = *(const float4*)(row + c);
        const float* ow = offset_w + (size_t)c * Kdim;
#pragma unroll
        for (int k = 0; k < Kdim; k++)
            acc[k] += hv.x * ow[k] + hv.y * ow[Kdim + k] + hv.z * ow[2 * Kdim + k]
                    + hv.w * ow[3 * Kdim + k];
        ushort4 hp;
        hp.x = (ushort)f2bf(hv.x); hp.y = (ushort)f2bf(hv.y);
        hp.z = (ushort)f2bf(hv.z); hp.w = (ushort)f2bf(hv.w);
        *(ushort4*)(h16 + (size_t)bt * Wdim + c) = hp;
    }
#pragma unroll
    for (int k = 0; k < Kdim; k++) {
#pragma unroll
        for (int m = 32; m > 0; m >>= 1) acc[k] += __shfl_xor(acc[k], m);
    }
    if (lane < Kdim) {
        float o = acc[lane] + offset_b[lane];
        float base = (float)t + (float)(lane - 3);
        float p = fminf(fmaxf(base + o, 0.f), (float)(Tdim - 1));
        pos[bt * Kdim + lane] = p;
    }
}

// ---------------- K2: deformable grouped conv; A dbuf LDS, B global->regs ----------------
// grid: (b*32 + tc)*8 + g ; 256 thr = 4 waves; wave = 64t x 32o
__global__ __launch_bounds__(256, 4) void k_conv(const ushort* __restrict__ h16,
                                                 const short* __restrict__ Wtb,
                                                 const float* __restrict__ conv_b,
                                                 const float* __restrict__ pos,
                                                 ushort* __restrict__ y16) {
    __shared__ short8v sA8[2][TT * 16];   // 2 x 16 KB

    int blk = blockIdx.x;
    int g  = blk & 7;
    int tc = (blk >> 3) & 31;
    int b  = blk >> 8;
    int t0 = tc * TT;
    int tid = threadIdx.x;
    int lane = tid & 63, wv = tid >> 6;
    int r15 = lane & 15, q = lane >> 4;

    const ushort* hb = h16 + (size_t)(b * Tdim) * Wdim + g * Cg;
    const short8v* WtbV = (const short8v*)Wtb + (size_t)(g * Kdim) * 2048;

    int scb = tid & 15;          // staging col-block (16B units)
    int sr0 = tid >> 4;          // staging base row (0..15)

    float4v acc[4][2];
#pragma unroll
    for (int tt = 0; tt < 4; tt++)
#pragma unroll
        for (int n = 0; n < 2; n++) acc[tt][n] = (float4v){0.f, 0.f, 0.f, 0.f};

#pragma unroll 1
    for (int k = 0; k < Kdim; k++) {
        // ---- issue B-frag loads (global, L2-resident; land during interp) ----
        short8v bfr[8];
#pragma unroll
        for (int n = 0; n < 2; n++)
#pragma unroll
            for (int kk = 0; kk < 4; kk++)
                bfr[n * 4 + kk] =
                    WtbV[(size_t)k * 2048 + (wv * 32 + n * 16 + r15) * 16 + kk * 4 + q];
        // ---- stage A(k) into buf[k&1]: gather + lerp, coalesced 256B rows ----
        short8v* buf = sA8[k & 1];
#pragma unroll
        for (int i = 0; i < 4; i++) {
            int r = sr0 + i * 16;
            float p = pos[(b * Tdim + t0 + r) * Kdim + k];
            int p0 = (int)p;
            float f = p - (float)p0;
            int p1 = min(p0 + 1, Tdim - 1);
            uint4 lo = *(const uint4*)(hb + (size_t)p0 * Wdim + scb * 8);
            uint4 hi = *(const uint4*)(hb + (size_t)p1 * Wdim + scb * 8);
            buf[r * 16 + (scb ^ (r & 7))] = lerp_pack(lo, hi, f);
        }
        __syncthreads();          // single barrier per tap (dbuf covers WAR)
        // ---- compute: 4 t-tiles x (4 ds_read + 8 MFMA) ----
#pragma unroll
        for (int tt = 0; tt < 4; tt++) {
            int r = tt * 16 + r15;
            short8v af[4];
#pragma unroll
            for (int kk = 0; kk < 4; kk++)
                af[kk] = buf[r * 16 + ((kk * 4 + q) ^ (r & 7))];
#pragma unroll
            for (int kk = 0; kk < 4; kk++) {
#pragma unroll
                for (int n = 0; n < 2; n++)
                    acc[tt][n] = __builtin_amdgcn_mfma_f32_16x16x32_bf16(
                        af[kk], bfr[n * 4 + kk], acc[tt][n], 0, 0, 0);
            }
        }
    }
    // ---- epilogue: acc -> swizzled fp32 LDS -> packed coalesced y16 stores ----
    __syncthreads();
    float* ep = (float*)sA8;     // 32 KB = 64 rows x 128 cols fp32
#pragma unroll
    for (int n = 0; n < 2; n++) {
        int colb = wv * 32 + n * 16 + r15;
        float bias = conv_b[g * Cg + colb];
#pragma unroll
        for (int tt = 0; tt < 4; tt++)
#pragma unroll
            for (int j = 0; j < 4; j++) {
                int row = tt * 16 + q * 4 + j;
                ep[row * 128 + (colb ^ ((row & 7) << 2))] = acc[tt][n][j] + bias;
            }
    }
    __syncthreads();
    int row = tid >> 2, c0 = (tid & 3) * 32;
    int sw = (row & 7) << 2;
    ushort* yp = y16 + (size_t)(b * Tdim + t0 + row) * Wdim + g * Cg + c0;
#pragma unroll
    for (int s = 0; s < 4; s++) {
        float4 va = *(const float4*)&ep[row * 128 + ((c0 + s * 8) ^ sw)];
        float4 vb = *(const float4*)&ep[row * 128 + ((c0 + s * 8 + 4) ^ sw)];
        uint4 o;
        o.x = pack2bf(va.x, va.y);
        o.y = pack2bf(va.z, va.w);
        o.z = pack2bf(vb.x, vb.y);
        o.w = pack2bf(vb.z, vb.w);
        *(uint4*)(yp + s * 8) = o;
    }
}

// ---------------- K3: LN + masked pool, wave-per-row, atomic accumulate ----------------
__global__ __launch_bounds__(256) void k_lnpool(const ushort* __restrict__ y16,
                                                const int* __restrict__ mask,
                                                float* __restrict__ s_sum) {
    int blk = blockIdx.x;
    int b = blk >> 6, ch = blk & 63;
    int tid = threadIdx.x;
    int lane = tid & 63, wv = tid >> 6;
    __shared__ float red[4 * Wdim];      // 16 KB

    float accv[2][8];
#pragma unroll
    for (int j = 0; j < 2; j++)
#pragma unroll
        for (int e = 0; e < 8; e++) accv[j][e] = 0.f;

    for (int i = 0; i < 8; i++) {
        int t = ch * 32 + wv * 8 + i;
        if (mask[b * Tdim + t]) continue;
        const ushort* yr = y16 + (size_t)(b * Tdim + t) * Wdim;
        float v[2][8];
        float s = 0.f, qq = 0.f;
#pragma unroll
        for (int j = 0; j < 2; j++) {
            uint4 u = *(const uint4*)(yr + lane * 8 + j * 512);
            const unsigned* pu = (const unsigned*)&u;
#pragma unroll
            for (int d = 0; d < 4; d++) {
                float lo = __uint_as_float(pu[d] << 16);
                float hi = __uint_as_float(pu[d] & 0xffff0000u);
                v[j][d * 2] = lo; v[j][d * 2 + 1] = hi;
                s += lo + hi; qq += lo * lo + hi * hi;
            }
        }
#pragma unroll
        for (int m = 32; m > 0; m >>= 1) { s += __shfl_xor(s, m); qq += __shfl_xor(qq, m); }
        float mu = s * (1.f / Wdim);
        float inv = rsqrtf(qq * (1.f / Wdim) - mu * mu + 1e-5f);
#pragma unroll
        for (int j = 0; j < 2; j++)
#pragma unroll
            for (int e = 0; e < 8; e++) accv[j][e] += (v[j][e] - mu) * inv;
    }
#pragma unroll
    for (int j = 0; j < 2; j++) {
        *(float4*)(&red[wv * Wdim + lane * 8 + j * 512]) =
            (float4){accv[j][0], accv[j][1], accv[j][2], accv[j][3]};
        *(float4*)(&red[wv * Wdim + lane * 8 + j * 512 + 4]) =
            (float4){accv[j][4], accv[j][5], accv[j][6], accv[j][7]};
    }
    __syncthreads();
#pragma unroll
    for (int e = 0; e < 4; e++) {
        int w = tid + e * 256;
        float a = red[w] + red[Wdim + w] + red[2 * Wdim + w] + red[3 * Wdim + w];
        atomicAdd(&s_sum[b * Wdim + w], a);
    }
}

// ---------------- K4: SE MLP + final projection -> out[b] ----------------
__global__ __launch_bounds__(256) void k_sefinal(const float* __restrict__ s_sum,
                                                 const int* __restrict__ mask,
                                                 const float* __restrict__ ln_g,
                                                 const float* __restrict__ ln_b,
                                                 const float* __restrict__ w1,
                                                 const float* __restrict__ b1,
                                                 const float* __restrict__ w2,
                                                 const float* __restrict__ b2,
                                                 const float* __restrict__ projw,
                                                 const float* __restrict__ projb,
                                                 float* __restrict__ out) {
    int b = blockIdx.x, tid = threadIdx.x;
    __shared__ float s[Wdim];
    __shared__ float hred[4][Hdim];
    __shared__ float hid[Hdim];
    __shared__ float rbuf[4];
    __shared__ float sLinv;
    int lane = tid & 63, wv = tid >> 6;

    int cnt = 0;
    for (int t = tid; t < Tdim; t += 256) cnt += (mask[b * Tdim + t] ? 0 : 1);
    float fc = (float)cnt;
#pragma unroll
    for (int off = 32; off > 0; off >>= 1) fc += __shfl_down(fc, off);
    if (lane == 0) rbuf[wv] = fc;
    __syncthreads();
    if (tid == 0) {
        float L = rbuf[0] + rbuf[1] + rbuf[2] + rbuf[3];
        sLinv = 1.f / fmaxf(L, 1.f);
    }
    __syncthreads();
    float Linv = sLinv;

    int w4 = tid * 4;
    float4 a = *(const float4*)(s_sum + b * Wdim + w4);
    float4 gg = *(const float4*)(ln_g + w4);
    float4 bb = *(const float4*)(ln_b + w4);
    s[w4 + 0] = gg.x * (a.x * Linv) + bb.x;
    s[w4 + 1] = gg.y * (a.y * Linv) + bb.y;
    s[w4 + 2] = gg.z * (a.z * Linv) + bb.z;
    s[w4 + 3] = gg.w * (a.w * Linv) + bb.w;
    __syncthreads();

    int j = tid & 63, p = tid >> 6;
    float ha = 0.f;
    for (int w = p * 256; w < (p + 1) * 256; ++w) ha += s[w] * w1[(size_t)w * Hdim + j];
    hred[p][j] = ha;
    __syncthreads();
    if (tid < Hdim)
        hid[tid] = fmaxf(hred[0][tid] + hred[1][tid] + hred[2][tid] + hred[3][tid] + b1[tid], 0.f);
    __syncthreads();

    float part = 0.f;
    for (int w = tid; w < Wdim; w += 256) {
        float ga = b2[w];
#pragma unroll 8
        for (int j2 = 0; j2 < Hdim; j2++) ga += hid[j2] * w2[(size_t)j2 * Wdim + w];
        float gate = 1.f / (1.f + expf(-ga));
        part += s[w] * gate * projw[w];
    }
#pragma unroll
    for (int off = 32; off > 0; off >>= 1) part += __shfl_down(part, off);
    __syncthreads();
    if (lane == 0) rbuf[wv] = part;
    __syncthreads();
    if (tid == 0) out[b] = rbuf[0] + rbuf[1] + rbuf[2] + rbuf[3] + projb[0];
}

extern "C" void kernel_launch(void* const* d_in, const int* in_sizes, int n_in,
                              void* d_out, int out_size, void* d_ws, size_t ws_size,
                              hipStream_t stream) {
    const float* h        = (const float*)d_in[0];
    const int*   mask     = (const int*)d_in[1];
    const float* offset_w = (const float*)d_in[2];
    const float* offset_b = (const float*)d_in[3];
    const float* conv_w   = (const float*)d_in[4];
    const float* conv_b   = (const float*)d_in[5];
    const float* ln_g     = (const float*)d_in[6];
    const float* ln_b     = (const float*)d_in[7];
    const float* se_w1    = (const float*)d_in[8];
    const float* se_b1    = (const float*)d_in[9];
    const float* se_w2    = (const float*)d_in[10];
    const float* se_b2    = (const float*)d_in[11];
    const float* proj_w   = (const float*)d_in[12];
    const float* proj_b   = (const float*)d_in[13];
    float* out = (float*)d_out;

    char* wsb = (char*)d_ws;
    float*  pos   = (float*)(wsb);                    //    229,376 B
    ushort* h16   = (ushort*)(wsb + 229376);          // 16,777,216 B
    short*  Wtb   = (short*)(wsb + 17006592);         //  1,835,008 B
    ushort* y16   = (ushort*)(wsb + 18841600);        // 16,777,216 B
    float*  s_sum = (float*)(wsb + 35618816);         //     16,384 B (total ~34 MB)

    k_pre<<<dim3(448 + Bdim * Tdim / 4), dim3(256), 0, stream>>>(conv_w, Wtb, h, offset_w,
                                                                 offset_b, pos, h16, s_sum);
    k_conv<<<dim3(Bdim * (Tdim / TT) * Gdim), dim3(256), 0, stream>>>(h16, Wtb, conv_b,
                                                                      pos, y16);
    k_lnpool<<<dim3(Bdim * 64), dim3(256), 0, stream>>>(y16, mask, s_sum);
    k_sefinal<<<dim3(Bdim), dim3(256), 0, stream>>>(s_sum, mask, ln_g, ln_b,
                                                    se_w1, se_b1, se_w2, se_b2,
                                                    proj_w, proj_b, out);
}